// Round 2
// baseline (171.701 us; speedup 1.0000x reference)
//
#include <hip/hip_runtime.h>
#include <hip/hip_bf16.h>

#define S_LEN 4096
#define D_DIM 64
#define NBATCH 4

typedef unsigned short u16;
typedef unsigned int u32;
typedef __attribute__((ext_vector_type(8))) __bf16 bf16x8;
typedef __attribute__((ext_vector_type(4))) float f32x4;

__device__ __forceinline__ u16 f_to_bf16u(float f) {
    union { float f; u32 u; } x; x.f = f;
    u32 r = x.u + 0x7fffu + ((x.u >> 16) & 1u);   // RNE; inputs finite
    return (u16)(r >> 16);
}

// ---------------------------------------------------------------------------
// QKV projection. p=blockIdx.y selects q/k/v. Q is PRE-SCALED by
// softmax_scale*log2(e) so the flash kernel needs no per-element multiply.
// V written transposed: Vt[b][d][s].
// ---------------------------------------------------------------------------
__global__ __launch_bounds__(256, 2)
void proj_qkv_kernel(const float* __restrict__ q, const float* __restrict__ k,
                     const float* __restrict__ v,
                     const float* __restrict__ Wq, const float* __restrict__ bq,
                     const float* __restrict__ Wk, const float* __restrict__ bk,
                     const float* __restrict__ Wv, const float* __restrict__ bv,
                     u16* __restrict__ Qb, u16* __restrict__ Kb, u16* __restrict__ Vt)
{
    __shared__ __align__(16) u16 vt[64 * 72];

    const int p = blockIdx.y;
    const float* inp  = (p == 0) ? q  : (p == 1) ? k  : v;
    const float* W    = (p == 0) ? Wq : (p == 1) ? Wk : Wv;
    const float* bias = (p == 0) ? bq : (p == 1) ? bk : bv;
    const float scl   = (p == 0) ? 0.18033688011112042f : 1.0f;  // 0.125*log2e

    const int tid  = threadIdx.x;
    const int wid  = tid >> 6;
    const int lane = tid & 63;
    const int ln   = lane & 15;
    const int qd   = lane >> 4;
    const int row0 = blockIdx.x * 64;
    const int r0w  = row0 + wid * 16;

    bf16x8 afrag[2];
#pragma unroll
    for (int c = 0; c < 2; ++c) {
        const float* src = inp + (r0w + ln) * 64 + c * 32 + qd * 8;
        float4 f0 = *(const float4*)src;
        float4 f1 = *(const float4*)(src + 4);
        bf16x8 a;
        a[0] = (__bf16)f0.x; a[1] = (__bf16)f0.y; a[2] = (__bf16)f0.z; a[3] = (__bf16)f0.w;
        a[4] = (__bf16)f1.x; a[5] = (__bf16)f1.y; a[6] = (__bf16)f1.z; a[7] = (__bf16)f1.w;
        afrag[c] = a;
    }

    bf16x8 bfrag[4][2];
    float  bcol[4];
#pragma unroll
    for (int nb = 0; nb < 4; ++nb) {
        bcol[nb] = bias[nb * 16 + ln];
#pragma unroll
        for (int c = 0; c < 2; ++c) {
            const float* src = W + (nb * 16 + ln) * 64 + c * 32 + qd * 8;
            float4 f0 = *(const float4*)src;
            float4 f1 = *(const float4*)(src + 4);
            bf16x8 b;
            b[0] = (__bf16)f0.x; b[1] = (__bf16)f0.y; b[2] = (__bf16)f0.z; b[3] = (__bf16)f0.w;
            b[4] = (__bf16)f1.x; b[5] = (__bf16)f1.y; b[6] = (__bf16)f1.z; b[7] = (__bf16)f1.w;
            bfrag[nb][c] = b;
        }
    }

    f32x4 acc[4];
#pragma unroll
    for (int nb = 0; nb < 4; ++nb) acc[nb] = (f32x4){0.f, 0.f, 0.f, 0.f};
#pragma unroll
    for (int c = 0; c < 2; ++c)
#pragma unroll
        for (int nb = 0; nb < 4; ++nb)
            acc[nb] = __builtin_amdgcn_mfma_f32_16x16x32_bf16(afrag[c], bfrag[nb][c], acc[nb], 0, 0, 0);

    if (p < 2) {
        u16* dst = (p == 0) ? Qb : Kb;
#pragma unroll
        for (int nb = 0; nb < 4; ++nb)
#pragma unroll
            for (int r = 0; r < 4; ++r) {
                int row = r0w + qd * 4 + r;
                dst[row * 64 + nb * 16 + ln] = f_to_bf16u((acc[nb][r] + bcol[nb]) * scl);
            }
    } else {
#pragma unroll
        for (int nb = 0; nb < 4; ++nb)
#pragma unroll
            for (int r = 0; r < 4; ++r)
                vt[(wid * 16 + qd * 4 + r) * 72 + nb * 16 + ln] = f_to_bf16u(acc[nb][r] + bcol[nb]);
        __syncthreads();
        const int d  = tid >> 2;
        const int sc = tid & 3;
        const int b  = row0 >> 12;
        const int sb = row0 & 4095;
        __align__(16) u16 tmp[16];
#pragma unroll
        for (int i = 0; i < 16; ++i) tmp[i] = vt[(sc * 16 + i) * 72 + d];
        u16* dstp = Vt + (size_t)b * (64 * S_LEN) + d * S_LEN + sb + sc * 16;
        *(uint4*)(dstp)     = *(const uint4*)(tmp);
        *(uint4*)(dstp + 8) = *(const uint4*)(tmp + 8);
    }
}

// ---------------------------------------------------------------------------
// Flash partial: max-free softmax, no barriers, direct global K/V loads.
// Computes S^T = K*Q^T per 16-row strip so P hits LDS as b64 writes.
// Block = (batch | 64-row band rb | j-chunk c); wave w = 16-row strip.
// All 4 waves share the same jt sequence -> L1 reuse of K/V tiles.
// Partials: Op bf16 unnormalized [pt*nch+c][16][64], Lp fp32 [pt*nch+c][16].
// nch==1 path writes normalized O directly in [b][s][64] layout, no Lp.
// ---------------------------------------------------------------------------
__global__ __launch_bounds__(256, 4)
void flash_part_kernel(const u16* __restrict__ Qb, const u16* __restrict__ Kb,
                       const u16* __restrict__ Vt, u16* __restrict__ Op,
                       float* __restrict__ Lp, const int cshift)
{
    __shared__ __align__(16) u16 pbuf[4][16 * 72];

    const int tid  = threadIdx.x;
    const int wid  = tid >> 6;
    const int lane = tid & 63;
    const int ln   = lane & 15;
    const int qd   = lane >> 4;

    const int nch   = 1 << cshift;
    const int bid   = blockIdx.x;
    const int batch = bid & 3;           // low bits -> XCD locality per batch
    const int pos   = bid >> 2;
    const int c     = pos & (nch - 1);
    const int rb    = pos >> cshift;     // 64-row band
    const int i0    = rb * 64 + wid * 16;

    // Q as B-operand: B[n=qrow=ln][k=d]
    const u16* qp = Qb + ((size_t)batch * S_LEN + i0 + ln) * 64 + qd * 8;
    bf16x8 qf[2];
    qf[0] = *(const bf16x8*)qp;
    qf[1] = *(const bf16x8*)(qp + 32);

    f32x4 oacc[4];
#pragma unroll
    for (int nb = 0; nb < 4; ++nb) oacc[nb] = (f32x4){0.f, 0.f, 0.f, 0.f};
    float lsum = 0.f;

    u16* pb = pbuf[wid];
    const u16* kbase = Kb + (size_t)batch * S_LEN * 64 + ln * 64 + qd * 8;
    const u16* vbase = Vt + (size_t)batch * (64 * S_LEN) + ln * S_LEN + qd * 8;

    const int jt0 = rb + ((c - rb) & (nch - 1));
    for (int jt = jt0; jt < 64; jt += nch) {
        const int j0 = jt * 64;

        bf16x8 kf[4][2], vf[4][2];
#pragma unroll
        for (int nb = 0; nb < 4; ++nb)
#pragma unroll
            for (int c2 = 0; c2 < 2; ++c2)
                kf[nb][c2] = *(const bf16x8*)(kbase + (j0 + nb * 16) * 64 + c2 * 32);
#pragma unroll
        for (int onb = 0; onb < 4; ++onb)
#pragma unroll
            for (int c2 = 0; c2 < 2; ++c2)
                vf[onb][c2] = *(const bf16x8*)(vbase + onb * (16 * S_LEN) + j0 + c2 * 32);

        // S^T slice: A = K (m = kcol), B = Q (n = qrow)
        f32x4 sacc[4];
#pragma unroll
        for (int nb = 0; nb < 4; ++nb) sacc[nb] = (f32x4){0.f, 0.f, 0.f, 0.f};
#pragma unroll
        for (int c2 = 0; c2 < 2; ++c2)
#pragma unroll
            for (int nb = 0; nb < 4; ++nb)
                sacc[nb] = __builtin_amdgcn_mfma_f32_16x16x32_bf16(kf[nb][c2], qf[c2], sacc[nb], 0, 0, 0);

        // exp (Q pre-scaled), anti-causal mask only on the diagonal tile,
        // per-lane l partial, pack 4 contiguous kcols -> one b64 LDS write.
#pragma unroll
        for (int nb = 0; nb < 4; ++nb) {
            float p0 = exp2f(sacc[nb][0]);
            float p1 = exp2f(sacc[nb][1]);
            float p2 = exp2f(sacc[nb][2]);
            float p3 = exp2f(sacc[nb][3]);
            if (jt == rb) {                       // mask: kcol < qrow -> 0
                int colb = j0 + nb * 16 + qd * 4;
                int rowg = i0 + ln;
                p0 = (colb + 0 < rowg) ? 0.f : p0;
                p1 = (colb + 1 < rowg) ? 0.f : p1;
                p2 = (colb + 2 < rowg) ? 0.f : p2;
                p3 = (colb + 3 < rowg) ? 0.f : p3;
            }
            lsum += (p0 + p1) + (p2 + p3);
            u32 w0 = (u32)f_to_bf16u(p0) | ((u32)f_to_bf16u(p1) << 16);
            u32 w1 = (u32)f_to_bf16u(p2) | ((u32)f_to_bf16u(p3) << 16);
            *(uint2*)(pb + ln * 72 + nb * 16 + qd * 4) = make_uint2(w0, w1);
        }

        // P back as A-operand (row = qrow = ln, k = kcol contiguous)
        bf16x8 pa0 = *(const bf16x8*)(pb + ln * 72 + qd * 8);
        bf16x8 pa1 = *(const bf16x8*)(pb + ln * 72 + 32 + qd * 8);
#pragma unroll
        for (int onb = 0; onb < 4; ++onb)
            oacc[onb] = __builtin_amdgcn_mfma_f32_16x16x32_bf16(pa0, vf[onb][0], oacc[onb], 0, 0, 0);
#pragma unroll
        for (int onb = 0; onb < 4; ++onb)
            oacc[onb] = __builtin_amdgcn_mfma_f32_16x16x32_bf16(pa1, vf[onb][1], oacc[onb], 0, 0, 0);
    }

    // l: reduce across qd groups (per-lane partials cover disjoint kcols)
    lsum += __shfl_xor(lsum, 16);
    lsum += __shfl_xor(lsum, 32);

    if (nch == 1) {
        float linv[4];
#pragma unroll
        for (int r = 0; r < 4; ++r) linv[r] = 1.0f / __shfl(lsum, qd * 4 + r);
        u16* ob = Op + ((size_t)batch * S_LEN + i0) * 64;
#pragma unroll
        for (int onb = 0; onb < 4; ++onb)
#pragma unroll
            for (int r = 0; r < 4; ++r)
                ob[(qd * 4 + r) * 64 + onb * 16 + ln] = f_to_bf16u(oacc[onb][r] * linv[r]);
    } else {
        const int pt = (batch * 64 + rb) * 4 + wid;
        u16* ob = Op + (size_t)(pt * nch + c) * 1024;
#pragma unroll
        for (int onb = 0; onb < 4; ++onb)
#pragma unroll
            for (int r = 0; r < 4; ++r)
                ob[(qd * 4 + r) * 64 + onb * 16 + ln] = f_to_bf16u(oacc[onb][r]);
        if (lane < 16) Lp[(pt * nch + c) * 16 + lane] = lsum;
    }
}

// ---------------------------------------------------------------------------
// Combine j-chunk partials (pure sums — max-free) + output projection.
// out = (sum_c O_c / sum_c l_c) @ Wp^T + bp, fp32 out.
// ---------------------------------------------------------------------------
__global__ __launch_bounds__(256, 2)
void combine_proj_kernel(const u16* __restrict__ Op, const float* __restrict__ Lp,
                         const float* __restrict__ Wp, const float* __restrict__ bp,
                         float* __restrict__ out, const int nch)
{
    const int tid  = threadIdx.x;
    const int wid  = tid >> 6;
    const int lane = tid & 63;
    const int ln   = lane & 15;
    const int qd   = lane >> 4;
    const int g    = blockIdx.x * 64 + wid * 16;   // wave's first row
    const int row  = g + ln;

    bf16x8 afrag[2];
    if (nch == 1) {
        const u16* op = Op + (size_t)row * 64 + qd * 8;
        afrag[0] = *(const bf16x8*)op;
        afrag[1] = *(const bf16x8*)(op + 32);
    } else {
        const int batch = row >> 12;
        const int sr    = row & 4095;
        const int rb    = sr >> 6;
        const int w     = (sr >> 4) & 3;
        const int pt    = (batch * 64 + rb) * 4 + w;
        float acc0[8], acc1[8];
#pragma unroll
        for (int j = 0; j < 8; ++j) { acc0[j] = 0.f; acc1[j] = 0.f; }
        float l = 0.f;
#pragma unroll
        for (int cc = 0; cc < 4; ++cc) {
            const u16* op = Op + (size_t)(pt * 4 + cc) * 1024 + ln * 64 + qd * 8;
            bf16x8 x0 = *(const bf16x8*)op;
            bf16x8 x1 = *(const bf16x8*)(op + 32);
#pragma unroll
            for (int j = 0; j < 8; ++j) { acc0[j] += (float)x0[j]; acc1[j] += (float)x1[j]; }
            l += Lp[(pt * 4 + cc) * 16 + ln];
        }
        float inv = 1.0f / l;
        bf16x8 a0, a1;
#pragma unroll
        for (int j = 0; j < 8; ++j) { a0[j] = (__bf16)(acc0[j] * inv); a1[j] = (__bf16)(acc1[j] * inv); }
        afrag[0] = a0; afrag[1] = a1;
    }

    bf16x8 bfrag[4][2];
    float  bcol[4];
#pragma unroll
    for (int nb = 0; nb < 4; ++nb) {
        bcol[nb] = bp[nb * 16 + ln];
#pragma unroll
        for (int c = 0; c < 2; ++c) {
            const float* src = Wp + (nb * 16 + ln) * 64 + c * 32 + qd * 8;
            float4 f0 = *(const float4*)src;
            float4 f1 = *(const float4*)(src + 4);
            bf16x8 b;
            b[0] = (__bf16)f0.x; b[1] = (__bf16)f0.y; b[2] = (__bf16)f0.z; b[3] = (__bf16)f0.w;
            b[4] = (__bf16)f1.x; b[5] = (__bf16)f1.y; b[6] = (__bf16)f1.z; b[7] = (__bf16)f1.w;
            bfrag[nb][c] = b;
        }
    }

    f32x4 acc[4];
#pragma unroll
    for (int nb = 0; nb < 4; ++nb) acc[nb] = (f32x4){0.f, 0.f, 0.f, 0.f};
#pragma unroll
    for (int c = 0; c < 2; ++c)
#pragma unroll
        for (int nb = 0; nb < 4; ++nb)
            acc[nb] = __builtin_amdgcn_mfma_f32_16x16x32_bf16(afrag[c], bfrag[nb][c], acc[nb], 0, 0, 0);

#pragma unroll
    for (int nb = 0; nb < 4; ++nb)
#pragma unroll
        for (int r = 0; r < 4; ++r) {
            int rowo = g + qd * 4 + r;
            out[(size_t)rowo * 64 + nb * 16 + ln] = acc[nb][r] + bcol[nb];
        }
}

extern "C" void kernel_launch(void* const* d_in, const int* in_sizes, int n_in,
                              void* d_out, int out_size, void* d_ws, size_t ws_size,
                              hipStream_t stream) {
    const float* q  = (const float*)d_in[0];
    const float* k  = (const float*)d_in[1];
    const float* v  = (const float*)d_in[2];
    const float* Wq = (const float*)d_in[3];
    const float* bq = (const float*)d_in[4];
    const float* Wk = (const float*)d_in[5];
    const float* bk = (const float*)d_in[6];
    const float* Wv = (const float*)d_in[7];
    const float* bv = (const float*)d_in[8];
    const float* Wp = (const float*)d_in[9];
    const float* bp = (const float*)d_in[10];
    float* out = (float*)d_out;

    const size_t NTOK = (size_t)NBATCH * S_LEN * D_DIM;   // 1,048,576
    u16* Qb = (u16*)d_ws;                                  // 2 MB
    u16* Kb = Qb + NTOK;                                   // 2 MB
    u16* Vt = Kb + NTOK;                                   // 2 MB
    u16* Op = Vt + NTOK;

    // 4-chunk flash-decoding path needs 6 MB + 8 MB (Op) + 256 KB (Lp).
    const size_t need4 = 3 * NTOK * 2 + (size_t)4096 * 1024 * 2 + (size_t)4096 * 16 * 4;
    int cshift = (ws_size >= need4) ? 2 : 0;
    int nch = 1 << cshift;
    float* Lp = (float*)(Op + (size_t)4096 * 1024);        // after Op (nch==4 layout)

    proj_qkv_kernel<<<dim3(256, 3), 256, 0, stream>>>(q, k, v, Wq, bq, Wk, bk, Wv, bv, Qb, Kb, Vt);
    flash_part_kernel<<<NBATCH * 64 * nch, 256, 0, stream>>>(Qb, Kb, Vt, Op, Lp, cshift);
    combine_proj_kernel<<<256, 256, 0, stream>>>(Op, Lp, Wp, bp, out, nch);
}

// Round 3
// 129.740 us; speedup vs baseline: 1.3234x; 1.3234x over previous
//
#include <hip/hip_runtime.h>
#include <hip/hip_bf16.h>

#define S_LEN 4096
#define D_DIM 64
#define NBATCH 4

typedef unsigned short u16;
typedef unsigned int u32;
typedef __attribute__((ext_vector_type(8))) __bf16 bf16x8;
typedef __attribute__((ext_vector_type(4))) float f32x4;
typedef __attribute__((ext_vector_type(16))) float f32x16;

__device__ __forceinline__ u16 f_to_bf16u(float f) {
    union { float f; u32 u; } x; x.f = f;
    u32 r = x.u + 0x7fffu + ((x.u >> 16) & 1u);   // RNE; inputs finite
    return (u16)(r >> 16);
}

// ---------------------------------------------------------------------------
// QKV projection. Q PRE-SCALED by 0.125*log2(e). V written transposed Vt[b][d][s].
// ---------------------------------------------------------------------------
__global__ __launch_bounds__(256, 2)
void proj_qkv_kernel(const float* __restrict__ q, const float* __restrict__ k,
                     const float* __restrict__ v,
                     const float* __restrict__ Wq, const float* __restrict__ bq,
                     const float* __restrict__ Wk, const float* __restrict__ bk,
                     const float* __restrict__ Wv, const float* __restrict__ bv,
                     u16* __restrict__ Qb, u16* __restrict__ Kb, u16* __restrict__ Vt)
{
    __shared__ __align__(16) u16 vt[64 * 72];

    const int p = blockIdx.y;
    const float* inp  = (p == 0) ? q  : (p == 1) ? k  : v;
    const float* W    = (p == 0) ? Wq : (p == 1) ? Wk : Wv;
    const float* bias = (p == 0) ? bq : (p == 1) ? bk : bv;
    const float scl   = (p == 0) ? 0.18033688011112042f : 1.0f;

    const int tid  = threadIdx.x;
    const int wid  = tid >> 6;
    const int lane = tid & 63;
    const int ln   = lane & 15;
    const int qd   = lane >> 4;
    const int row0 = blockIdx.x * 64;
    const int r0w  = row0 + wid * 16;

    bf16x8 afrag[2];
#pragma unroll
    for (int c = 0; c < 2; ++c) {
        const float* src = inp + (r0w + ln) * 64 + c * 32 + qd * 8;
        float4 f0 = *(const float4*)src;
        float4 f1 = *(const float4*)(src + 4);
        bf16x8 a;
        a[0] = (__bf16)f0.x; a[1] = (__bf16)f0.y; a[2] = (__bf16)f0.z; a[3] = (__bf16)f0.w;
        a[4] = (__bf16)f1.x; a[5] = (__bf16)f1.y; a[6] = (__bf16)f1.z; a[7] = (__bf16)f1.w;
        afrag[c] = a;
    }

    bf16x8 bfrag[4][2];
    float  bcol[4];
#pragma unroll
    for (int nb = 0; nb < 4; ++nb) {
        bcol[nb] = bias[nb * 16 + ln];
#pragma unroll
        for (int c = 0; c < 2; ++c) {
            const float* src = W + (nb * 16 + ln) * 64 + c * 32 + qd * 8;
            float4 f0 = *(const float4*)src;
            float4 f1 = *(const float4*)(src + 4);
            bf16x8 b;
            b[0] = (__bf16)f0.x; b[1] = (__bf16)f0.y; b[2] = (__bf16)f0.z; b[3] = (__bf16)f0.w;
            b[4] = (__bf16)f1.x; b[5] = (__bf16)f1.y; b[6] = (__bf16)f1.z; b[7] = (__bf16)f1.w;
            bfrag[nb][c] = b;
        }
    }

    f32x4 acc[4];
#pragma unroll
    for (int nb = 0; nb < 4; ++nb) acc[nb] = (f32x4){0.f, 0.f, 0.f, 0.f};
#pragma unroll
    for (int c = 0; c < 2; ++c)
#pragma unroll
        for (int nb = 0; nb < 4; ++nb)
            acc[nb] = __builtin_amdgcn_mfma_f32_16x16x32_bf16(afrag[c], bfrag[nb][c], acc[nb], 0, 0, 0);

    if (p < 2) {
        u16* dst = (p == 0) ? Qb : Kb;
#pragma unroll
        for (int nb = 0; nb < 4; ++nb)
#pragma unroll
            for (int r = 0; r < 4; ++r) {
                int row = r0w + qd * 4 + r;
                dst[row * 64 + nb * 16 + ln] = f_to_bf16u((acc[nb][r] + bcol[nb]) * scl);
            }
    } else {
#pragma unroll
        for (int nb = 0; nb < 4; ++nb)
#pragma unroll
            for (int r = 0; r < 4; ++r)
                vt[(wid * 16 + qd * 4 + r) * 72 + nb * 16 + ln] = f_to_bf16u(acc[nb][r] + bcol[nb]);
        __syncthreads();
        const int d  = tid >> 2;
        const int sc = tid & 3;
        const int b  = row0 >> 12;
        const int sb = row0 & 4095;
        __align__(16) u16 tmp[16];
#pragma unroll
        for (int i = 0; i < 16; ++i) tmp[i] = vt[(sc * 16 + i) * 72 + d];
        u16* dstp = Vt + (size_t)b * (64 * S_LEN) + d * S_LEN + sb + sc * 16;
        *(uint4*)(dstp)     = *(const uint4*)(tmp);
        *(uint4*)(dstp + 8) = *(const uint4*)(tmp + 8);
    }
}

// ---------------------------------------------------------------------------
// Flash partial v3: 32x32x16 MFMA, LDS-staged K/V (double buffered, one
// barrier/iter), XOR-swizzled chunks, anti-causal mask with balanced
// complementary band pairing, max-free softmax, 4 j-chunks.
// Block: 4 waves x 32 qrows = 128 rows. Grid 512 = 2 blocks/CU.
// ---------------------------------------------------------------------------
__global__ __launch_bounds__(256, 2)
void flash_kernel(const u16* __restrict__ Qb, const u16* __restrict__ Kb,
                  const u16* __restrict__ Vt, u16* __restrict__ Op,
                  float* __restrict__ Lp)
{
    __shared__ __align__(16) u16 kv[2][2][64 * 64];   // [buf][K|V][row*64]; 32 KB
    __shared__ __align__(16) u16 pbuf[4][32 * 64];    // per-wave P; 16 KB

    const int tid  = threadIdx.x;
    const int wid  = tid >> 6;
    const int lane = tid & 63;
    const int l31  = lane & 31;
    const int lh   = lane >> 5;
    const int sw7  = l31 & 7;          // row-swizzle key (rows r and r+32 share it)

    // balanced complementary mapping: bid and bid+256 -> bands (rb, 31-rb)
    const int bid   = blockIdx.x;
    const int half  = bid >> 8;
    const int idx   = bid & 255;
    const int batch = idx & 3;
    const int vv_   = idx >> 2;        // 0..63
    const int c     = vv_ & 3;         // j-chunk
    const int rb16  = vv_ >> 2;        // 0..15
    const int rb    = half ? (31 - rb16) : rb16;
    const int first = 2 * rb;
    const int jt0   = first + ((c - first) & 3);
    const int i0w   = rb * 128 + wid * 32;   // wave's first qrow

    // Q as B-operand: B[n=qrow=l31][k = c2*16 + lh*8 + j]
    const u16* qrow = Qb + ((size_t)batch * S_LEN + i0w + l31) * 64;
    bf16x8 qf[4];
#pragma unroll
    for (int c2 = 0; c2 < 4; ++c2)
        qf[c2] = *(const bf16x8*)(qrow + c2 * 16 + lh * 8);

    f32x16 o0, o1;
#pragma unroll
    for (int r = 0; r < 16; ++r) { o0[r] = 0.f; o1[r] = 0.f; }
    float lsum = 0.f;

    // staging roles: tid<128 -> K tile, else V tile; 64B (4 chunks) per thread
    const int  srow = (tid & 127) >> 1;
    const int  sch0 = (tid & 1) * 4;
    const u16* kg   = Kb + ((size_t)batch * S_LEN + srow) * 64 + sch0 * 8;
    const u16* vg   = Vt + (size_t)batch * (64 * S_LEN) + srow * S_LEN + sch0 * 8;
    uint4 pf0, pf1, pf2, pf3;

    u16* pw = &pbuf[wid][0];
    int cur = 0;

    if (jt0 < 64) {
        {   // prefetch first tile
            const int j0 = jt0 * 64;
            if (tid < 128) {
                const uint4* g = (const uint4*)(kg + (size_t)j0 * 64);
                pf0 = g[0]; pf1 = g[1]; pf2 = g[2]; pf3 = g[3];
            } else {
                const uint4* g = (const uint4*)(vg + j0);
                pf0 = g[0]; pf1 = g[1]; pf2 = g[2]; pf3 = g[3];
            }
            u16* base = &kv[0][(tid >> 7)][srow * 64];
            *(uint4*)(base + ((sch0 + 0) ^ (srow & 7)) * 8) = pf0;
            *(uint4*)(base + ((sch0 + 1) ^ (srow & 7)) * 8) = pf1;
            *(uint4*)(base + ((sch0 + 2) ^ (srow & 7)) * 8) = pf2;
            *(uint4*)(base + ((sch0 + 3) ^ (srow & 7)) * 8) = pf3;
        }

        for (int jt = jt0; jt < 64; jt += 4) {
            __syncthreads();
            const int j0   = jt * 64;
            const bool more = (jt + 4) < 64;
            if (more) {
                const int jn = (jt + 4) * 64;
                if (tid < 128) {
                    const uint4* g = (const uint4*)(kg + (size_t)jn * 64);
                    pf0 = g[0]; pf1 = g[1]; pf2 = g[2]; pf3 = g[3];
                } else {
                    const uint4* g = (const uint4*)(vg + jn);
                    pf0 = g[0]; pf1 = g[1]; pf2 = g[2]; pf3 = g[3];
                }
            }

            const u16* kb = &kv[cur][0][0];
            const u16* vb = &kv[cur][1][0];

            // ---- S^T = K * Q^T : 2 mtiles x 4 kchunks
            f32x16 s0, s1;
#pragma unroll
            for (int r = 0; r < 16; ++r) { s0[r] = 0.f; s1[r] = 0.f; }
#pragma unroll
            for (int c2 = 0; c2 < 4; ++c2) {
                const int ch = (2 * c2 + lh) ^ sw7;
                bf16x8 k0 = *(const bf16x8*)(kb + l31 * 64 + ch * 8);
                bf16x8 k1 = *(const bf16x8*)(kb + (32 + l31) * 64 + ch * 8);
                s0 = __builtin_amdgcn_mfma_f32_32x32x16_bf16(k0, qf[c2], s0, 0, 0, 0);
                s1 = __builtin_amdgcn_mfma_f32_32x32x16_bf16(k1, qf[c2], s1, 0, 0, 0);
            }

            // ---- exp2 (Q pre-scaled), mask on straddling tiles, P -> LDS
            const bool needmask = (j0 < i0w + 32);
            const int  qr = i0w + l31;
#pragma unroll
            for (int m = 0; m < 2; ++m) {
#pragma unroll
                for (int g = 0; g < 4; ++g) {
                    float p0, p1, p2, p3;
                    {
                        const f32x16& s = m ? s1 : s0;
                        p0 = exp2f(s[g * 4 + 0]);
                        p1 = exp2f(s[g * 4 + 1]);
                        p2 = exp2f(s[g * 4 + 2]);
                        p3 = exp2f(s[g * 4 + 3]);
                    }
                    if (needmask) {
                        const int kcol = j0 + m * 32 + 8 * g + 4 * lh;
                        p0 = (kcol + 0 < qr) ? 0.f : p0;
                        p1 = (kcol + 1 < qr) ? 0.f : p1;
                        p2 = (kcol + 2 < qr) ? 0.f : p2;
                        p3 = (kcol + 3 < qr) ? 0.f : p3;
                    }
                    lsum += (p0 + p1) + (p2 + p3);
                    u32 w0 = (u32)f_to_bf16u(p0) | ((u32)f_to_bf16u(p1) << 16);
                    u32 w1 = (u32)f_to_bf16u(p2) | ((u32)f_to_bf16u(p3) << 16);
                    *(uint2*)(pw + l31 * 64 + m * 32 + g * 8 + 4 * lh) = make_uint2(w0, w1);
                }
            }

            // ---- O += P * V : 4 kchunks x 2 ntiles
#pragma unroll
            for (int cc = 0; cc < 4; ++cc) {
                bf16x8 pa = *(const bf16x8*)(pw + l31 * 64 + cc * 16 + lh * 8);
                const int ch = (2 * cc + lh) ^ sw7;
                bf16x8 va = *(const bf16x8*)(vb + l31 * 64 + ch * 8);
                bf16x8 vbq = *(const bf16x8*)(vb + (32 + l31) * 64 + ch * 8);
                o0 = __builtin_amdgcn_mfma_f32_32x32x16_bf16(pa, va, o0, 0, 0, 0);
                o1 = __builtin_amdgcn_mfma_f32_32x32x16_bf16(pa, vbq, o1, 0, 0, 0);
            }

            if (more) {
                u16* base = &kv[cur ^ 1][(tid >> 7)][srow * 64];
                *(uint4*)(base + ((sch0 + 0) ^ (srow & 7)) * 8) = pf0;
                *(uint4*)(base + ((sch0 + 1) ^ (srow & 7)) * 8) = pf1;
                *(uint4*)(base + ((sch0 + 2) ^ (srow & 7)) * 8) = pf2;
                *(uint4*)(base + ((sch0 + 3) ^ (srow & 7)) * 8) = pf3;
            }
            cur ^= 1;
        }
    }

    // ---- epilogue: write unnormalized partials + l
    const int pt = ((batch * 32 + rb) * 4 + wid);
    u16* ob = Op + ((size_t)pt * 4 + c) * 2048;
#pragma unroll
    for (int r = 0; r < 16; ++r) {
        const int qrl = (r & 3) + 8 * (r >> 2) + 4 * lh;
        ob[qrl * 64 + l31]      = f_to_bf16u(o0[r]);
        ob[qrl * 64 + 32 + l31] = f_to_bf16u(o1[r]);
    }
    lsum += __shfl_xor(lsum, 32);
    if (lane < 32) Lp[((size_t)pt * 4 + c) * 32 + lane] = lsum;
}

// ---------------------------------------------------------------------------
// Combine j-chunk partials (pure sums) + output projection (fp32 out).
// ---------------------------------------------------------------------------
__global__ __launch_bounds__(256, 2)
void combine_proj_kernel(const u16* __restrict__ Op, const float* __restrict__ Lp,
                         const float* __restrict__ Wp, const float* __restrict__ bp,
                         float* __restrict__ out)
{
    const int tid  = threadIdx.x;
    const int wid  = tid >> 6;
    const int lane = tid & 63;
    const int ln   = lane & 15;
    const int qd   = lane >> 4;
    const int g    = blockIdx.x * 64 + wid * 16;
    const int row  = g + ln;

    const int batch = row >> 12;
    const int sr    = row & 4095;
    const int pt    = (batch * 32 + (sr >> 7)) * 4 + ((sr >> 5) & 3);
    const int rl    = sr & 31;

    float acc0[8], acc1[8];
#pragma unroll
    for (int j = 0; j < 8; ++j) { acc0[j] = 0.f; acc1[j] = 0.f; }
    float l = 0.f;
#pragma unroll
    for (int cc = 0; cc < 4; ++cc) {
        const u16* op = Op + ((size_t)pt * 4 + cc) * 2048 + rl * 64 + qd * 8;
        bf16x8 x0 = *(const bf16x8*)op;
        bf16x8 x1 = *(const bf16x8*)(op + 32);
#pragma unroll
        for (int j = 0; j < 8; ++j) { acc0[j] += (float)x0[j]; acc1[j] += (float)x1[j]; }
        l += Lp[((size_t)pt * 4 + cc) * 32 + rl];
    }
    float inv = 1.0f / l;
    bf16x8 afrag[2];
#pragma unroll
    for (int j = 0; j < 8; ++j) { afrag[0][j] = (__bf16)(acc0[j] * inv); afrag[1][j] = (__bf16)(acc1[j] * inv); }

    bf16x8 bfrag[4][2];
    float  bcol[4];
#pragma unroll
    for (int nb = 0; nb < 4; ++nb) {
        bcol[nb] = bp[nb * 16 + ln];
#pragma unroll
        for (int cc = 0; cc < 2; ++cc) {
            const float* src = Wp + (nb * 16 + ln) * 64 + cc * 32 + qd * 8;
            float4 f0 = *(const float4*)src;
            float4 f1 = *(const float4*)(src + 4);
            bf16x8 b;
            b[0] = (__bf16)f0.x; b[1] = (__bf16)f0.y; b[2] = (__bf16)f0.z; b[3] = (__bf16)f0.w;
            b[4] = (__bf16)f1.x; b[5] = (__bf16)f1.y; b[6] = (__bf16)f1.z; b[7] = (__bf16)f1.w;
            bfrag[nb][cc] = b;
        }
    }

    f32x4 acc[4];
#pragma unroll
    for (int nb = 0; nb < 4; ++nb) acc[nb] = (f32x4){0.f, 0.f, 0.f, 0.f};
#pragma unroll
    for (int cc = 0; cc < 2; ++cc)
#pragma unroll
        for (int nb = 0; nb < 4; ++nb)
            acc[nb] = __builtin_amdgcn_mfma_f32_16x16x32_bf16(afrag[cc], bfrag[nb][cc], acc[nb], 0, 0, 0);

#pragma unroll
    for (int nb = 0; nb < 4; ++nb)
#pragma unroll
        for (int r = 0; r < 4; ++r) {
            int rowo = g + qd * 4 + r;
            out[(size_t)rowo * 64 + nb * 16 + ln] = acc[nb][r] + bcol[nb];
        }
}

extern "C" void kernel_launch(void* const* d_in, const int* in_sizes, int n_in,
                              void* d_out, int out_size, void* d_ws, size_t ws_size,
                              hipStream_t stream) {
    const float* q  = (const float*)d_in[0];
    const float* k  = (const float*)d_in[1];
    const float* v  = (const float*)d_in[2];
    const float* Wq = (const float*)d_in[3];
    const float* bq = (const float*)d_in[4];
    const float* Wk = (const float*)d_in[5];
    const float* bk = (const float*)d_in[6];
    const float* Wv = (const float*)d_in[7];
    const float* bv = (const float*)d_in[8];
    const float* Wp = (const float*)d_in[9];
    const float* bp = (const float*)d_in[10];
    float* out = (float*)d_out;

    const size_t NTOK = (size_t)NBATCH * S_LEN * D_DIM;   // 1,048,576
    u16* Qb = (u16*)d_ws;                                  // 2 MB
    u16* Kb = Qb + NTOK;                                   // 2 MB
    u16* Vt = Kb + NTOK;                                   // 2 MB
    u16* Op = Vt + NTOK;                                   // 8 MB
    float* Lp = (float*)(Op + (size_t)4096 * 1024);        // 256 KB

    proj_qkv_kernel<<<dim3(256, 3), 256, 0, stream>>>(q, k, v, Wq, bq, Wk, bk, Wv, bv, Qb, Kb, Vt);
    flash_kernel<<<512, 256, 0, stream>>>(Qb, Kb, Vt, Op, Lp);
    combine_proj_kernel<<<256, 256, 0, stream>>>(Op, Lp, Wp, bp, out);
}